// Round 1
// baseline (1129.051 us; speedup 1.0000x reference)
//
#include <hip/hip_runtime.h>

typedef unsigned short u16;
typedef __attribute__((ext_vector_type(8))) short short8;
typedef __attribute__((ext_vector_type(4))) float floatx4;

#define NN 50000
#define NE 1600000
#define BN_EPS 1e-5f
#define NPB 8                 // dst nodes owned per k_edge2 block
#define NSCAN 196             // ceil(NN/256)

__device__ __forceinline__ float bfu(u16 u) {
    union { unsigned u32; float f; } v; v.u32 = ((unsigned)u) << 16; return v.f;
}
__device__ __forceinline__ u16 f2bf(float f) {
    union { float f; unsigned u; } v; v.f = f;
    unsigned r = v.u + 0x7FFFu + ((v.u >> 16) & 1u);
    return (u16)(r >> 16);
}
// mode m: 1 = buffers hold float32, 0 = buffers hold bf16
__device__ __forceinline__ float ldf(const void* p, int i, int m) {
    return m ? ((const float*)p)[i] : bfu(((const u16*)p)[i]);
}

// K0: dtype detection (f32 reinterpreted as bf16 -> random-exponent garbage).
__global__ __launch_bounds__(256) void k_detect(const u16* __restrict__ x, int* __restrict__ mode) {
    float mx = 0.f;
    for (int i = threadIdx.x; i < 4096; i += 256) mx = fmaxf(mx, fabsf(bfu(x[i])));
#pragma unroll
    for (int o = 32; o > 0; o >>= 1) mx = fmaxf(mx, __shfl_down(mx, o));
    __shared__ float s[4];
    if ((threadIdx.x & 63) == 0) s[threadIdx.x >> 6] = mx;
    __syncthreads();
    if (threadIdx.x == 0) {
        float m2 = fmaxf(fmaxf(s[0], s[1]), fmaxf(s[2], s[3]));
        mode[0] = (m2 > 1e4f) ? 1 : 0;
    }
}

// K0b: canonicalize all MFMA-consumed weights to bf16 ws copies.
// Layout in dst: Wfe0[16384] | We1[8192] | Wfn0[16384] | Wn1[8192] | Wfn1[16384]
__global__ __launch_bounds__(256) void k_cvtw(const void* __restrict__ W0, const void* __restrict__ W1,
                                              const void* __restrict__ W2, const void* __restrict__ W3,
                                              const void* __restrict__ W4,
                                              u16* __restrict__ dst, const int* __restrict__ mf) {
    int m = mf[0];
    int i = blockIdx.x * 256 + threadIdx.x;   // 65536 total
    const void* src; int off;
    if (i < 16384)      { src = W0; off = i; }
    else if (i < 24576) { src = W1; off = i - 16384; }
    else if (i < 40960) { src = W2; off = i - 24576; }
    else if (i < 49152) { src = W3; off = i - 40960; }
    else                { src = W4; off = i - 49152; }
    dst[i] = m ? f2bf(((const float*)src)[off]) : ((const u16*)src)[off];
}

// K1: n1_l0[n][c] = relu(sum_i x[n][i]*Wn0[c][i])  [50000 x 64] bf16. LDS-staged Wn0.
__global__ __launch_bounds__(256) void k_enc0(const void* __restrict__ x, const void* __restrict__ Wn,
                                              u16* __restrict__ n1, const int* __restrict__ mf) {
    int m = mf[0];
    __shared__ float Wns[64 * 17];
    __shared__ float xsh[4][16];
    int t = threadIdx.x;
    int n0 = blockIdx.x * 4;
    for (int i = t; i < 1024; i += 256) Wns[(i >> 4) * 17 + (i & 15)] = ldf(Wn, i, m);
    if (t < 64) xsh[t >> 4][t & 15] = ldf(x, n0 * 16 + t, m);
    __syncthreads();
    int n = t >> 6, c = t & 63;
    float acc = 0.f;
#pragma unroll
    for (int i = 0; i < 16; i++) acc += xsh[n][i] * Wns[c * 17 + i];
    n1[(n0 + n) * 64 + c] = f2bf(fmaxf(acc, 0.f));
}

// K2: per-node positive / negative edge_attr sums (rank-1 segment-sum trick)
//     + dst-degree histogram for the counting sort.
__global__ __launch_bounds__(256) void k_esum(const void* __restrict__ ea, const int* __restrict__ ei,
                                              float* __restrict__ sp, float* __restrict__ sn,
                                              int* __restrict__ cnt, const int* __restrict__ mf) {
    int m = mf[0];
    int e = blockIdx.x * 256 + threadIdx.x;
    float a = ldf(ea, e, m);
    int d = ei[NE + e];
    atomicAdd(cnt + d, 1);
    if (a > 0.f) atomicAdd(sp + d, a);
    else if (a < 0.f) atomicAdd(sn + d, a);
}

// Scan phase 1: per-256-block sums of cnt
__global__ __launch_bounds__(256) void k_scan1(const int* __restrict__ cnt, int* __restrict__ bsum) {
    int t = threadIdx.x;
    int idx = blockIdx.x * 256 + t;
    int v = (idx < NN) ? cnt[idx] : 0;
#pragma unroll
    for (int o = 32; o > 0; o >>= 1) v += __shfl_down(v, o);
    __shared__ int s[4];
    if ((t & 63) == 0) s[t >> 6] = v;
    __syncthreads();
    if (t == 0) bsum[blockIdx.x] = s[0] + s[1] + s[2] + s[3];
}

// Scan phase 2: exclusive scan of the 196 block sums (single block)
__global__ __launch_bounds__(256) void k_scan2(int* __restrict__ bsum) {
    __shared__ int sh[256];
    int t = threadIdx.x;
    int v = (t < NSCAN) ? bsum[t] : 0;
    sh[t] = v;
    __syncthreads();
    for (int o = 1; o < 256; o <<= 1) {
        int u = (t >= o) ? sh[t - o] : 0;
        __syncthreads();
        sh[t] += u;
        __syncthreads();
    }
    if (t < NSCAN) bsum[t] = sh[t] - v;   // exclusive
}

// Scan phase 3: per-block exclusive scan + offset -> start[] (CSR row ptr) & cursor[]
__global__ __launch_bounds__(256) void k_scan3(const int* __restrict__ cnt, const int* __restrict__ bsum,
                                               int* __restrict__ start, int* __restrict__ cursor) {
    __shared__ int sh[256];
    int t = threadIdx.x;
    int idx = blockIdx.x * 256 + t;
    int v = (idx < NN) ? cnt[idx] : 0;
    sh[t] = v;
    __syncthreads();
    for (int o = 1; o < 256; o <<= 1) {
        int u = (t >= o) ? sh[t - o] : 0;
        __syncthreads();
        sh[t] += u;
        __syncthreads();
    }
    int excl = sh[t] - v + bsum[blockIdx.x];
    if (idx < NN) { start[idx] = excl; cursor[idx] = excl; }
    if (idx == NN - 1) start[NN] = excl + v;
}

// Scatter: place each edge into its dst-sorted slot. Pack src node id (16b) and
// dst&7 (the local id within the owning 8-node block) into perm; copy ea as f32.
__global__ __launch_bounds__(256) void k_scatter(const void* __restrict__ ea, const int* __restrict__ ei,
                                                 int* __restrict__ cursor, int* __restrict__ perm,
                                                 float* __restrict__ eas, const int* __restrict__ mf) {
    int m = mf[0];
    int e = blockIdx.x * 256 + threadIdx.x;
    int d = ei[NE + e];
    int s = ei[e];
    int p = atomicAdd(cursor + d, 1);
    perm[p] = s | ((d & 7) << 16);
    eas[p] = ldf(ea, e, m);
}

// K_PN: P[j] = sum_k relu(We0[k])*Wfe0[j][64+k]; N[j] = sum_k min(We0[k],0)*Wfe0[j][64+k]
__global__ void k_pn(const void* __restrict__ We0, const void* __restrict__ Wfe0,
                     float* __restrict__ PN, const int* __restrict__ mf) {
    int m = mf[0];
    int j = threadIdx.x;  // 128
    float p = 0.f, n = 0.f;
    for (int k = 0; k < 64; k++) {
        float w = ldf(We0, k, m);
        float wf = ldf(Wfe0, j * 128 + 64 + k, m);
        p += fmaxf(w, 0.f) * wf;
        n += fminf(w, 0.f) * wf;
    }
    PN[j] = p; PN[128 + j] = n;
}

// K34: fused node MLP l0 + BN + node encoder l1 -> n1_l1 [50000 x 64] bf16. MFMA, 64 nodes/block.
__global__ __launch_bounds__(256) void k_node_l0(
    const u16* __restrict__ n1l0, const float* __restrict__ sp, const float* __restrict__ sn,
    const void* __restrict__ We0, const u16* __restrict__ Wfn0c, const void* __restrict__ bfn0,
    const void* __restrict__ g0, const void* __restrict__ b0,
    const void* __restrict__ rm0, const void* __restrict__ rv0,
    const u16* __restrict__ Wn1c, u16* __restrict__ n1l1, const int* __restrict__ mf) {
    int m = mf[0];
    __shared__ __align__(16) u16 fs[64][136];
    __shared__ __align__(16) u16 xs[64][136];
    int t = threadIdx.x;
    int n0 = blockIdx.x * 64;
    {   // fs[row][col] = concat(analytic agg_l0, n1_l0), bf16
        int col = t & 127;
        int rbase = t >> 7;              // 0 or 1
        float wp = 0.f, wn = 0.f;
        if (col < 64) { float w0 = ldf(We0, col, m); wp = fmaxf(w0, 0.f); wn = fminf(w0, 0.f); }
#pragma unroll
        for (int i = 0; i < 32; i++) {
            int row = rbase + 2 * i;
            int n = n0 + row;
            float v = 0.f;
            if (n < NN) v = (col < 64) ? (wp * sp[n] + wn * sn[n]) : bfu(n1l0[n * 64 + col - 64]);
            fs[row][col] = f2bf(v);
        }
    }
    __syncthreads();
    int lane = t & 63, w = t >> 6, q = lane >> 4, nidx = lane & 15;
    // GEMM1: x1 = BN(relu(fs @ Wfn0^T + bfn0)) -> xs  (wave w: nodes w*16..w*16+15)
    {
        const u16* ar = &fs[w * 16 + nidx][0];
        short8 a0 = *(const short8*)&ar[q * 8];
        short8 a1 = *(const short8*)&ar[32 + q * 8];
        short8 a2 = *(const short8*)&ar[64 + q * 8];
        short8 a3 = *(const short8*)&ar[96 + q * 8];
#pragma unroll
        for (int jt = 0; jt < 8; jt++) {
            int j = jt * 16 + nidx;
            const u16* wr = Wfn0c + j * 128;
            floatx4 acc = {0.f, 0.f, 0.f, 0.f};
            acc = __builtin_amdgcn_mfma_f32_16x16x32_bf16(a0, *(const short8*)&wr[q * 8], acc, 0, 0, 0);
            acc = __builtin_amdgcn_mfma_f32_16x16x32_bf16(a1, *(const short8*)&wr[32 + q * 8], acc, 0, 0, 0);
            acc = __builtin_amdgcn_mfma_f32_16x16x32_bf16(a2, *(const short8*)&wr[64 + q * 8], acc, 0, 0, 0);
            acc = __builtin_amdgcn_mfma_f32_16x16x32_bf16(a3, *(const short8*)&wr[96 + q * 8], acc, 0, 0, 0);
            float bias = ldf(bfn0, j, m);
            float sc = ldf(g0, j, m) * rsqrtf(ldf(rv0, j, m) + BN_EPS);
            float sh = ldf(b0, j, m) - ldf(rm0, j, m) * sc;
#pragma unroll
            for (int r = 0; r < 4; r++) {
                int row = w * 16 + q * 4 + r;    // D: row=(lane>>4)*4+reg, col=lane&15
                xs[row][j] = f2bf(fmaxf(acc[r] + bias, 0.f) * sc + sh);
            }
        }
    }
    __syncthreads();
    // GEMM2: n1_l1 = relu(xs @ Wn1^T)  [64 x 64]
    {
        const u16* ar = &xs[w * 16 + nidx][0];
        short8 a0 = *(const short8*)&ar[q * 8];
        short8 a1 = *(const short8*)&ar[32 + q * 8];
        short8 a2 = *(const short8*)&ar[64 + q * 8];
        short8 a3 = *(const short8*)&ar[96 + q * 8];
#pragma unroll
        for (int jt = 0; jt < 4; jt++) {
            int j = jt * 16 + nidx;
            const u16* wr = Wn1c + j * 128;
            floatx4 acc = {0.f, 0.f, 0.f, 0.f};
            acc = __builtin_amdgcn_mfma_f32_16x16x32_bf16(a0, *(const short8*)&wr[q * 8], acc, 0, 0, 0);
            acc = __builtin_amdgcn_mfma_f32_16x16x32_bf16(a1, *(const short8*)&wr[32 + q * 8], acc, 0, 0, 0);
            acc = __builtin_amdgcn_mfma_f32_16x16x32_bf16(a2, *(const short8*)&wr[64 + q * 8], acc, 0, 0, 0);
            acc = __builtin_amdgcn_mfma_f32_16x16x32_bf16(a3, *(const short8*)&wr[96 + q * 8], acc, 0, 0, 0);
#pragma unroll
            for (int r = 0; r < 4; r++) {
                int row = w * 16 + q * 4 + r;
                int n = n0 + row;
                if (n < NN) n1l1[n * 64 + j] = f2bf(fmaxf(acc[r], 0.f));
            }
        }
    }
}

// K5v2: dst-owned fused edge pipeline. Each block owns NPB=8 consecutive dst nodes,
// processes their in-edges (dst-sorted via perm) in 16-edge MFMA chunks, accumulates
// e1' into LDS accs[8][64] (LDS atomics), writes agg once — NO global atomics.
__global__ __launch_bounds__(256) void k_edge2(
    const float* __restrict__ eas, const int* __restrict__ perm, const int* __restrict__ startp,
    const u16* __restrict__ n1l0,
    const u16* __restrict__ Wfe0c, const void* __restrict__ bfe0,
    const float* __restrict__ PN,
    const u16* __restrict__ We1c,
    float* __restrict__ agg, const int* __restrict__ mf) {
    int m = mf[0];
    __shared__ __align__(16) u16 h0s[16][72];
    __shared__ __align__(16) u16 h1s[16][136];
    __shared__ float dstv[NPB][64];
    __shared__ float accs[NPB][64];
    __shared__ float aes[16];
    __shared__ int srcs[16];
    __shared__ int lids[16];
    int t = threadIdx.x;
    int n0 = blockIdx.x * NPB;
    int s0 = startp[n0], s1 = startp[n0 + NPB];
    // Preload owned dst-node vectors (reused by every edge of the block), zero accumulators.
    for (int i = t; i < NPB * 64; i += 256) {
        int lid = i >> 6, c = i & 63;
        dstv[lid][c] = bfu(n1l0[(n0 + lid) * 64 + c]);
        accs[lid][c] = 0.f;
    }
    int lane = t & 63, w = t >> 6, q = lane >> 4, nidx = lane & 15;
    // Hoist all chunk-invariant weights into registers.
    int j0 = (2 * w) * 16 + nidx, j1 = (2 * w + 1) * 16 + nidx;
    const u16* wr0 = Wfe0c + j0 * 128;
    const u16* wr1 = Wfe0c + j1 * 128;
    short8 w0a = *(const short8*)&wr0[q * 8];
    short8 w0b = *(const short8*)&wr0[32 + q * 8];
    short8 w1a = *(const short8*)&wr1[q * 8];
    short8 w1b = *(const short8*)&wr1[32 + q * 8];
    float bias0 = ldf(bfe0, j0, m), bias1 = ldf(bfe0, j1, m);
    float P0 = PN[j0], N0 = PN[128 + j0];
    float P1 = PN[j1], N1 = PN[128 + j1];
    int c2 = w * 16 + nidx;
    const u16* wr2 = We1c + c2 * 128;
    short8 w2_0 = *(const short8*)&wr2[q * 8];
    short8 w2_1 = *(const short8*)&wr2[32 + q * 8];
    short8 w2_2 = *(const short8*)&wr2[64 + q * 8];
    short8 w2_3 = *(const short8*)&wr2[96 + q * 8];
    __syncthreads();

    for (int cb = s0; cb < s1; cb += 16) {
        if (t < 16) {
            int gi = cb + t;
            int valid = gi < s1;
            int v = valid ? perm[gi] : 0;
            srcs[t] = v & 0xFFFF;
            lids[t] = valid ? ((v >> 16) & 7) : -1;
            aes[t] = valid ? eas[gi] : 0.f;
        }
        __syncthreads();
        // h0[e][c] = n1l0[src][c] + n1l0[dst][c]   (dst side from LDS preload)
#pragma unroll
        for (int i = 0; i < 4; i++) {
            int idx = t + i * 256;
            int e = idx >> 6, c = idx & 63;
            int lid = lids[e];
            float v = bfu(n1l0[srcs[e] * 64 + c]) + (lid >= 0 ? dstv[lid][c] : 0.f);
            h0s[e][c] = f2bf(v);
        }
        __syncthreads();
        // GEMM1: h1 = relu(h0 @ Wfe0[:, :64]^T + bfe0 + rank1(ea))  -> h1s [16 x 128]
        {
            short8 a0 = *(const short8*)&h0s[nidx][q * 8];
            short8 a1 = *(const short8*)&h0s[nidx][32 + q * 8];
            {
                floatx4 acc = {0.f, 0.f, 0.f, 0.f};
                acc = __builtin_amdgcn_mfma_f32_16x16x32_bf16(a0, w0a, acc, 0, 0, 0);
                acc = __builtin_amdgcn_mfma_f32_16x16x32_bf16(a1, w0b, acc, 0, 0, 0);
#pragma unroll
                for (int r = 0; r < 4; r++) {
                    int e = q * 4 + r;
                    float a = aes[e];
                    float v = acc[r] + bias0 + a * (a > 0.f ? P0 : N0);
                    h1s[e][j0] = f2bf(fmaxf(v, 0.f));
                }
            }
            {
                floatx4 acc = {0.f, 0.f, 0.f, 0.f};
                acc = __builtin_amdgcn_mfma_f32_16x16x32_bf16(a0, w1a, acc, 0, 0, 0);
                acc = __builtin_amdgcn_mfma_f32_16x16x32_bf16(a1, w1b, acc, 0, 0, 0);
#pragma unroll
                for (int r = 0; r < 4; r++) {
                    int e = q * 4 + r;
                    float a = aes[e];
                    float v = acc[r] + bias1 + a * (a > 0.f ? P1 : N1);
                    h1s[e][j1] = f2bf(fmaxf(v, 0.f));
                }
            }
        }
        __syncthreads();
        // GEMM2: e1' = relu(h1 @ We1^T), accumulate per-dst in LDS.
        {
            floatx4 acc = {0.f, 0.f, 0.f, 0.f};
            acc = __builtin_amdgcn_mfma_f32_16x16x32_bf16(*(const short8*)&h1s[nidx][q * 8],       w2_0, acc, 0, 0, 0);
            acc = __builtin_amdgcn_mfma_f32_16x16x32_bf16(*(const short8*)&h1s[nidx][32 + q * 8],  w2_1, acc, 0, 0, 0);
            acc = __builtin_amdgcn_mfma_f32_16x16x32_bf16(*(const short8*)&h1s[nidx][64 + q * 8],  w2_2, acc, 0, 0, 0);
            acc = __builtin_amdgcn_mfma_f32_16x16x32_bf16(*(const short8*)&h1s[nidx][96 + q * 8],  w2_3, acc, 0, 0, 0);
#pragma unroll
            for (int r = 0; r < 4; r++) {
                int e = q * 4 + r;
                int lid = lids[e];
                if (lid >= 0) atomicAdd(&accs[lid][c2], fmaxf(acc[r], 0.f));
            }
        }
        __syncthreads();   // protect meta/h0s/h1s for next chunk; orders final accs
    }
    // Single coalesced non-atomic write of this block's 8 owned rows.
    for (int i = t; i < NPB * 64; i += 256) {
        int lid = i >> 6, c = i & 63;
        agg[(n0 + lid) * 64 + c] = accs[lid][c];
    }
}

// K6: node MLP l1 + BN -> d_out. MFMA, 64 nodes/block.
__global__ __launch_bounds__(256) void k_node_l1(
    const u16* __restrict__ n1l1, const float* __restrict__ agg,
    const u16* __restrict__ Wfn1c, const void* __restrict__ bfn1,
    const void* __restrict__ g1, const void* __restrict__ b1,
    const void* __restrict__ rm1, const void* __restrict__ rv1,
    void* __restrict__ out, const int* __restrict__ mf) {
    int m = mf[0];
    __shared__ __align__(16) u16 fs[64][136];
    int t = threadIdx.x;
    int n0 = blockIdx.x * 64;
    {
        int col = t & 127;
        int rbase = t >> 7;
#pragma unroll
        for (int i = 0; i < 32; i++) {
            int row = rbase + 2 * i;
            int n = n0 + row;
            float v = 0.f;
            if (n < NN) v = (col < 64) ? agg[n * 64 + col] : bfu(n1l1[n * 64 + col - 64]);
            fs[row][col] = f2bf(v);
        }
    }
    __syncthreads();
    int lane = t & 63, w = t >> 6, q = lane >> 4, nidx = lane & 15;
    const u16* ar = &fs[w * 16 + nidx][0];
    short8 a0 = *(const short8*)&ar[q * 8];
    short8 a1 = *(const short8*)&ar[32 + q * 8];
    short8 a2 = *(const short8*)&ar[64 + q * 8];
    short8 a3 = *(const short8*)&ar[96 + q * 8];
#pragma unroll
    for (int jt = 0; jt < 8; jt++) {
        int j = jt * 16 + nidx;
        const u16* wr = Wfn1c + j * 128;
        floatx4 acc = {0.f, 0.f, 0.f, 0.f};
        acc = __builtin_amdgcn_mfma_f32_16x16x32_bf16(a0, *(const short8*)&wr[q * 8], acc, 0, 0, 0);
        acc = __builtin_amdgcn_mfma_f32_16x16x32_bf16(a1, *(const short8*)&wr[32 + q * 8], acc, 0, 0, 0);
        acc = __builtin_amdgcn_mfma_f32_16x16x32_bf16(a2, *(const short8*)&wr[64 + q * 8], acc, 0, 0, 0);
        acc = __builtin_amdgcn_mfma_f32_16x16x32_bf16(a3, *(const short8*)&wr[96 + q * 8], acc, 0, 0, 0);
        float bias = ldf(bfn1, j, m);
        float sc = ldf(g1, j, m) * rsqrtf(ldf(rv1, j, m) + BN_EPS);
        float sh = ldf(b1, j, m) - ldf(rm1, j, m) * sc;
#pragma unroll
        for (int r = 0; r < 4; r++) {
            int row = w * 16 + q * 4 + r;
            int n = n0 + row;
            if (n < NN) {
                float v = fmaxf(acc[r] + bias, 0.f) * sc + sh;
                if (m) ((float*)out)[n * 128 + j] = v;
                else   ((u16*)out)[n * 128 + j] = f2bf(v);
            }
        }
    }
}

extern "C" void kernel_launch(void* const* d_in, const int* in_sizes, int n_in,
                              void* d_out, int out_size, void* d_ws, size_t ws_size,
                              hipStream_t stream) {
    const void* x    = d_in[0];
    const void* ea   = d_in[1];
    const int*  ei   = (const int*)d_in[2];
    const void* Wn0  = d_in[3];
    const void* We0  = d_in[4];
    const void* Wfn0 = d_in[5];
    const void* bfn0 = d_in[6];
    const void* Wfe0 = d_in[7];
    const void* bfe0 = d_in[8];
    const void* g0   = d_in[9];
    const void* b0   = d_in[10];
    const void* rm0  = d_in[11];
    const void* rv0  = d_in[12];
    const void* Wn1  = d_in[13];
    const void* We1  = d_in[14];
    const void* Wfn1 = d_in[15];
    const void* bfn1 = d_in[16];
    // d_in[17]/d_in[18] (l1_Wfe/l1_bfe): dead — layer-1 edge output discarded
    const void* g1   = d_in[19];
    const void* b1   = d_in[20];
    const void* rm1  = d_in[21];
    const void* rv1  = d_in[22];

    float* wsf    = (float*)d_ws;
    float* agg    = wsf;                          // 3,200,000 f32
    u16*   n1l0   = (u16*)(wsf + 3200000);        // 3.2M u16
    u16*   n1l1   = (u16*)(wsf + 4800000);        // 3.2M u16
    float* sp     = wsf + 6400000;                // 50,000
    float* sn     = wsf + 6450000;                // 50,000
    int*   cnt    = (int*)(wsf + 6500000);        // 50,000
    int*   start  = (int*)(wsf + 6550000);        // 50,001
    int*   cursor = (int*)(wsf + 6600004);        // 50,000
    int*   bsum   = (int*)(wsf + 6650004);        // 256
    float* PN     = wsf + 6650260;                // 256
    u16*   Wc     = (u16*)(wsf + 6650516);        // 65,536 u16 canonical weights
    int*   mode   = (int*)(wsf + 6683284);        // 1
    int*   perm   = (int*)(wsf + 6683288);        // 1,600,000 (src | lid<<16, dst-sorted)
    float* eas    = wsf + 8283288;                // 1,600,000 (ea in dst-sorted order, f32)
    u16* Wfe0c = Wc;
    u16* We1c  = Wc + 16384;
    u16* Wfn0c = Wc + 24576;
    u16* Wn1c  = Wc + 40960;
    u16* Wfn1c = Wc + 49152;

    // Zero sp + sn + cnt (contiguous). agg no longer needs zeroing: k_edge2 fully writes it.
    hipMemsetAsync(sp, 0, 150000 * sizeof(float), stream);

    k_detect<<<1, 256, 0, stream>>>((const u16*)x, mode);
    k_cvtw<<<256, 256, 0, stream>>>(Wfe0, We1, Wfn0, Wn1, Wfn1, Wc, mode);
    k_enc0<<<12500, 256, 0, stream>>>(x, Wn0, n1l0, mode);
    k_esum<<<6250, 256, 0, stream>>>(ea, ei, sp, sn, cnt, mode);
    k_scan1<<<NSCAN, 256, 0, stream>>>(cnt, bsum);
    k_scan2<<<1, 256, 0, stream>>>(bsum);
    k_scan3<<<NSCAN, 256, 0, stream>>>(cnt, bsum, start, cursor);
    k_pn<<<1, 128, 0, stream>>>(We0, Wfe0, PN, mode);
    k_scatter<<<6250, 256, 0, stream>>>(ea, ei, cursor, perm, eas, mode);
    k_node_l0<<<782, 256, 0, stream>>>(n1l0, sp, sn, We0, Wfn0c, bfn0,
                                       g0, b0, rm0, rv0, Wn1c, n1l1, mode);
    k_edge2<<<NN / NPB, 256, 0, stream>>>(eas, perm, start, n1l0, Wfe0c, bfe0,
                                          PN, We1c, agg, mode);
    k_node_l1<<<782, 256, 0, stream>>>(n1l1, agg, Wfn1c, bfn1,
                                       g1, b1, rm1, rv1, d_out, mode);
}

// Round 2
// 904.582 us; speedup vs baseline: 1.2481x; 1.2481x over previous
//
#include <hip/hip_runtime.h>

typedef unsigned short u16;
typedef __attribute__((ext_vector_type(8))) short short8;
typedef __attribute__((ext_vector_type(4))) float floatx4;

#define NN 50000
#define NE 1600000
#define BN_EPS 1e-5f
#define NSCAN 196             // ceil(NN/256)

__device__ __forceinline__ float bfu(u16 u) {
    union { unsigned u32; float f; } v; v.u32 = ((unsigned)u) << 16; return v.f;
}
__device__ __forceinline__ u16 f2bf(float f) {
    union { float f; unsigned u; } v; v.f = f;
    unsigned r = v.u + 0x7FFFu + ((v.u >> 16) & 1u);
    return (u16)(r >> 16);
}
// mode m: 1 = buffers hold float32, 0 = buffers hold bf16
__device__ __forceinline__ float ldf(const void* p, int i, int m) {
    return m ? ((const float*)p)[i] : bfu(((const u16*)p)[i]);
}

// K0: dtype detection (f32 reinterpreted as bf16 -> random-exponent garbage).
__global__ __launch_bounds__(256) void k_detect(const u16* __restrict__ x, int* __restrict__ mode) {
    float mx = 0.f;
    for (int i = threadIdx.x; i < 4096; i += 256) mx = fmaxf(mx, fabsf(bfu(x[i])));
#pragma unroll
    for (int o = 32; o > 0; o >>= 1) mx = fmaxf(mx, __shfl_down(mx, o));
    __shared__ float s[4];
    if ((threadIdx.x & 63) == 0) s[threadIdx.x >> 6] = mx;
    __syncthreads();
    if (threadIdx.x == 0) {
        float m2 = fmaxf(fmaxf(s[0], s[1]), fmaxf(s[2], s[3]));
        mode[0] = (m2 > 1e4f) ? 1 : 0;
    }
}

// K0b: canonicalize all MFMA-consumed weights to bf16 ws copies.
// Layout in dst: Wfe0[16384] | We1[8192] | Wfn0[16384] | Wn1[8192] | Wfn1[16384]
__global__ __launch_bounds__(256) void k_cvtw(const void* __restrict__ W0, const void* __restrict__ W1,
                                              const void* __restrict__ W2, const void* __restrict__ W3,
                                              const void* __restrict__ W4,
                                              u16* __restrict__ dst, const int* __restrict__ mf) {
    int m = mf[0];
    int i = blockIdx.x * 256 + threadIdx.x;   // 65536 total
    const void* src; int off;
    if (i < 16384)      { src = W0; off = i; }
    else if (i < 24576) { src = W1; off = i - 16384; }
    else if (i < 40960) { src = W2; off = i - 24576; }
    else if (i < 49152) { src = W3; off = i - 40960; }
    else                { src = W4; off = i - 49152; }
    dst[i] = m ? f2bf(((const float*)src)[off]) : ((const u16*)src)[off];
}

// K1: n1_l0[n][c] = relu(sum_i x[n][i]*Wn0[c][i])  [50000 x 64] bf16. LDS-staged Wn0.
__global__ __launch_bounds__(256) void k_enc0(const void* __restrict__ x, const void* __restrict__ Wn,
                                              u16* __restrict__ n1, const int* __restrict__ mf) {
    int m = mf[0];
    __shared__ float Wns[64 * 17];
    __shared__ float xsh[4][16];
    int t = threadIdx.x;
    int n0 = blockIdx.x * 4;
    for (int i = t; i < 1024; i += 256) Wns[(i >> 4) * 17 + (i & 15)] = ldf(Wn, i, m);
    if (t < 64) xsh[t >> 4][t & 15] = ldf(x, n0 * 16 + t, m);
    __syncthreads();
    int n = t >> 6, c = t & 63;
    float acc = 0.f;
#pragma unroll
    for (int i = 0; i < 16; i++) acc += xsh[n][i] * Wns[c * 17 + i];
    n1[(n0 + n) * 64 + c] = f2bf(fmaxf(acc, 0.f));
}

// K2: per-node positive / negative edge_attr sums (rank-1 segment-sum trick)
//     + dst-degree histogram for the counting sort.
__global__ __launch_bounds__(256) void k_esum(const void* __restrict__ ea, const int* __restrict__ ei,
                                              float* __restrict__ sp, float* __restrict__ sn,
                                              int* __restrict__ cnt, const int* __restrict__ mf) {
    int m = mf[0];
    int e = blockIdx.x * 256 + threadIdx.x;
    float a = ldf(ea, e, m);
    int d = ei[NE + e];
    atomicAdd(cnt + d, 1);
    if (a > 0.f) atomicAdd(sp + d, a);
    else if (a < 0.f) atomicAdd(sn + d, a);
}

// Scan phase 1: per-256-block sums of cnt
__global__ __launch_bounds__(256) void k_scan1(const int* __restrict__ cnt, int* __restrict__ bsum) {
    int t = threadIdx.x;
    int idx = blockIdx.x * 256 + t;
    int v = (idx < NN) ? cnt[idx] : 0;
#pragma unroll
    for (int o = 32; o > 0; o >>= 1) v += __shfl_down(v, o);
    __shared__ int s[4];
    if ((t & 63) == 0) s[t >> 6] = v;
    __syncthreads();
    if (t == 0) bsum[blockIdx.x] = s[0] + s[1] + s[2] + s[3];
}

// Scan phase 2: exclusive scan of the 196 block sums (single block)
__global__ __launch_bounds__(256) void k_scan2(int* __restrict__ bsum) {
    __shared__ int sh[256];
    int t = threadIdx.x;
    int v = (t < NSCAN) ? bsum[t] : 0;
    sh[t] = v;
    __syncthreads();
    for (int o = 1; o < 256; o <<= 1) {
        int u = (t >= o) ? sh[t - o] : 0;
        __syncthreads();
        sh[t] += u;
        __syncthreads();
    }
    if (t < NSCAN) bsum[t] = sh[t] - v;   // exclusive
}

// Scan phase 3: per-block exclusive scan + offset -> cursor[] (scatter cursors)
__global__ __launch_bounds__(256) void k_scan3(const int* __restrict__ cnt, const int* __restrict__ bsum,
                                               int* __restrict__ cursor) {
    __shared__ int sh[256];
    int t = threadIdx.x;
    int idx = blockIdx.x * 256 + t;
    int v = (idx < NN) ? cnt[idx] : 0;
    sh[t] = v;
    __syncthreads();
    for (int o = 1; o < 256; o <<= 1) {
        int u = (t >= o) ? sh[t - o] : 0;
        __syncthreads();
        sh[t] += u;
        __syncthreads();
    }
    int excl = sh[t] - v + bsum[blockIdx.x];
    if (idx < NN) cursor[idx] = excl;
}

// Scatter: one packed 8B record per edge into its dst-sorted slot.
// meta = src | dst<<16 (both < 65536); y = edge_attr as f32 bits.
__global__ __launch_bounds__(256) void k_scatter(const void* __restrict__ ea, const int* __restrict__ ei,
                                                 int* __restrict__ cursor, int2* __restrict__ edata,
                                                 const int* __restrict__ mf) {
    int m = mf[0];
    int e = blockIdx.x * 256 + threadIdx.x;
    int d = ei[NE + e];
    int s = ei[e];
    float a = ldf(ea, e, m);
    int p = atomicAdd(cursor + d, 1);
    int2 v;
    v.x = (int)((unsigned)s | ((unsigned)d << 16));
    v.y = __float_as_int(a);
    edata[p] = v;
}

// K_PN: P[j] = sum_k relu(We0[k])*Wfe0[j][64+k]; N[j] = sum_k min(We0[k],0)*Wfe0[j][64+k]
__global__ void k_pn(const void* __restrict__ We0, const void* __restrict__ Wfe0,
                     float* __restrict__ PN, const int* __restrict__ mf) {
    int m = mf[0];
    int j = threadIdx.x;  // 128
    float p = 0.f, n = 0.f;
    for (int k = 0; k < 64; k++) {
        float w = ldf(We0, k, m);
        float wf = ldf(Wfe0, j * 128 + 64 + k, m);
        p += fmaxf(w, 0.f) * wf;
        n += fminf(w, 0.f) * wf;
    }
    PN[j] = p; PN[128 + j] = n;
}

// K34: fused node MLP l0 + BN + node encoder l1 -> n1_l1 [50000 x 64] bf16. MFMA, 64 nodes/block.
__global__ __launch_bounds__(256) void k_node_l0(
    const u16* __restrict__ n1l0, const float* __restrict__ sp, const float* __restrict__ sn,
    const void* __restrict__ We0, const u16* __restrict__ Wfn0c, const void* __restrict__ bfn0,
    const void* __restrict__ g0, const void* __restrict__ b0,
    const void* __restrict__ rm0, const void* __restrict__ rv0,
    const u16* __restrict__ Wn1c, u16* __restrict__ n1l1, const int* __restrict__ mf) {
    int m = mf[0];
    __shared__ __align__(16) u16 fs[64][136];
    __shared__ __align__(16) u16 xs[64][136];
    int t = threadIdx.x;
    int n0 = blockIdx.x * 64;
    {   // fs[row][col] = concat(analytic agg_l0, n1_l0), bf16
        int col = t & 127;
        int rbase = t >> 7;              // 0 or 1
        float wp = 0.f, wn = 0.f;
        if (col < 64) { float w0 = ldf(We0, col, m); wp = fmaxf(w0, 0.f); wn = fminf(w0, 0.f); }
#pragma unroll
        for (int i = 0; i < 32; i++) {
            int row = rbase + 2 * i;
            int n = n0 + row;
            float v = 0.f;
            if (n < NN) v = (col < 64) ? (wp * sp[n] + wn * sn[n]) : bfu(n1l0[n * 64 + col - 64]);
            fs[row][col] = f2bf(v);
        }
    }
    __syncthreads();
    int lane = t & 63, w = t >> 6, q = lane >> 4, nidx = lane & 15;
    // GEMM1: x1 = BN(relu(fs @ Wfn0^T + bfn0)) -> xs  (wave w: nodes w*16..w*16+15)
    {
        const u16* ar = &fs[w * 16 + nidx][0];
        short8 a0 = *(const short8*)&ar[q * 8];
        short8 a1 = *(const short8*)&ar[32 + q * 8];
        short8 a2 = *(const short8*)&ar[64 + q * 8];
        short8 a3 = *(const short8*)&ar[96 + q * 8];
#pragma unroll
        for (int jt = 0; jt < 8; jt++) {
            int j = jt * 16 + nidx;
            const u16* wr = Wfn0c + j * 128;
            floatx4 acc = {0.f, 0.f, 0.f, 0.f};
            acc = __builtin_amdgcn_mfma_f32_16x16x32_bf16(a0, *(const short8*)&wr[q * 8], acc, 0, 0, 0);
            acc = __builtin_amdgcn_mfma_f32_16x16x32_bf16(a1, *(const short8*)&wr[32 + q * 8], acc, 0, 0, 0);
            acc = __builtin_amdgcn_mfma_f32_16x16x32_bf16(a2, *(const short8*)&wr[64 + q * 8], acc, 0, 0, 0);
            acc = __builtin_amdgcn_mfma_f32_16x16x32_bf16(a3, *(const short8*)&wr[96 + q * 8], acc, 0, 0, 0);
            float bias = ldf(bfn0, j, m);
            float sc = ldf(g0, j, m) * rsqrtf(ldf(rv0, j, m) + BN_EPS);
            float sh = ldf(b0, j, m) - ldf(rm0, j, m) * sc;
#pragma unroll
            for (int r = 0; r < 4; r++) {
                int row = w * 16 + q * 4 + r;    // D: row=(lane>>4)*4+reg, col=lane&15
                xs[row][j] = f2bf(fmaxf(acc[r] + bias, 0.f) * sc + sh);
            }
        }
    }
    __syncthreads();
    // GEMM2: n1_l1 = relu(xs @ Wn1^T)  [64 x 64]
    {
        const u16* ar = &xs[w * 16 + nidx][0];
        short8 a0 = *(const short8*)&ar[q * 8];
        short8 a1 = *(const short8*)&ar[32 + q * 8];
        short8 a2 = *(const short8*)&ar[64 + q * 8];
        short8 a3 = *(const short8*)&ar[96 + q * 8];
#pragma unroll
        for (int jt = 0; jt < 4; jt++) {
            int j = jt * 16 + nidx;
            const u16* wr = Wn1c + j * 128;
            floatx4 acc = {0.f, 0.f, 0.f, 0.f};
            acc = __builtin_amdgcn_mfma_f32_16x16x32_bf16(a0, *(const short8*)&wr[q * 8], acc, 0, 0, 0);
            acc = __builtin_amdgcn_mfma_f32_16x16x32_bf16(a1, *(const short8*)&wr[32 + q * 8], acc, 0, 0, 0);
            acc = __builtin_amdgcn_mfma_f32_16x16x32_bf16(a2, *(const short8*)&wr[64 + q * 8], acc, 0, 0, 0);
            acc = __builtin_amdgcn_mfma_f32_16x16x32_bf16(a3, *(const short8*)&wr[96 + q * 8], acc, 0, 0, 0);
#pragma unroll
            for (int r = 0; r < 4; r++) {
                int row = w * 16 + q * 4 + r;
                int n = n0 + row;
                if (n < NN) n1l1[n * 64 + j] = f2bf(fmaxf(acc[r], 0.f));
            }
        }
    }
}

// K5v3: fused edge pipeline on dst-SORTED edges, one 16-edge tile per block
// (massively parallel like r0), with in-tile segmented reduction so global
// atomics drop from 64/edge to ~64/distinct-dst (~10x fewer).
__global__ __launch_bounds__(256) void k_edge3(
    const int2* __restrict__ edata, const u16* __restrict__ n1l0,
    const u16* __restrict__ Wfe0c, const void* __restrict__ bfe0,
    const float* __restrict__ PN, const u16* __restrict__ We1c,
    float* __restrict__ agg, const int* __restrict__ mf) {
    int m = mf[0];
    __shared__ __align__(16) u16 h0s[16][72];
    __shared__ __align__(16) u16 h1s[16][136];
    __shared__ float hacc[16][68];
    __shared__ float aes[16];
    __shared__ int dsts[16];
    __shared__ int segs[16];
    int t = threadIdx.x;
    int e0 = blockIdx.x * 16;
    // Every lane loads its edge record (q-duplicated across the wave).
    int2 ed = edata[e0 + (t & 15)];
    if (t < 16) {
        dsts[t] = (int)(((unsigned)ed.x) >> 16);
        aes[t] = __int_as_float(ed.y);
    }
    // zero hacc
    for (int i = t; i < 16 * 68; i += 256) ((float*)hacc)[i] = 0.f;
    // segs: run-head index per edge (wave-0 only; same-wave LDS RAW is in-order)
    if (t < 16) {
        int s = t;
        while (s > 0 && dsts[s - 1] == dsts[s]) s--;
        segs[t] = s;
    }
    int lane = t & 63, w = t >> 6;
    // Gather h0 = n1l0[src] + n1l0[dst]; edge meta via shfl broadcast (no barrier needed).
#pragma unroll
    for (int i = 0; i < 4; i++) {
        int idx = t + i * 256;
        int e = idx >> 6, c = idx & 63;           // e is wave-uniform per iteration
        unsigned me = (unsigned)__shfl(ed.x, e);
        int srcn = (int)(me & 0xFFFFu);
        int dstn = (int)(me >> 16);
        float v = bfu(n1l0[srcn * 64 + c]) + bfu(n1l0[dstn * 64 + c]);
        h0s[e][c] = f2bf(v);
    }
    __syncthreads();
    int q = lane >> 4, nidx = lane & 15;
    // GEMM1: h1 = relu(h0 @ Wfe0[:, :64]^T + bfe0 + rank1(ea))  -> h1s [16 x 128]
    {
        short8 a0 = *(const short8*)&h0s[nidx][q * 8];
        short8 a1 = *(const short8*)&h0s[nidx][32 + q * 8];
#pragma unroll
        for (int jj = 0; jj < 2; jj++) {
            int jt = 2 * w + jj;
            int j = jt * 16 + nidx;
            const u16* wrow = Wfe0c + j * 128;
            short8 b0 = *(const short8*)&wrow[q * 8];
            short8 b1 = *(const short8*)&wrow[32 + q * 8];
            floatx4 acc = {0.f, 0.f, 0.f, 0.f};
            acc = __builtin_amdgcn_mfma_f32_16x16x32_bf16(a0, b0, acc, 0, 0, 0);
            acc = __builtin_amdgcn_mfma_f32_16x16x32_bf16(a1, b1, acc, 0, 0, 0);
            float bias = ldf(bfe0, j, m);
            float Pj = PN[j], Nj = PN[128 + j];
#pragma unroll
            for (int r = 0; r < 4; r++) {
                int e = q * 4 + r;
                float a = aes[e];
                float v = acc[r] + bias + a * (a > 0.f ? Pj : Nj);
                h1s[e][j] = f2bf(fmaxf(v, 0.f));
            }
        }
    }
    __syncthreads();
    // GEMM2: e1' = relu(h1 @ We1^T); per-lane run-merge, LDS-atomic into hacc.
    {
        int c2 = w * 16 + nidx;
        const u16* wrow = We1c + c2 * 128;
        floatx4 acc = {0.f, 0.f, 0.f, 0.f};
#pragma unroll
        for (int ks = 0; ks < 4; ks++) {
            short8 aa = *(const short8*)&h1s[nidx][ks * 32 + q * 8];
            short8 bb = *(const short8*)&wrow[ks * 32 + q * 8];
            acc = __builtin_amdgcn_mfma_f32_16x16x32_bf16(aa, bb, acc, 0, 0, 0);
        }
        int eb = q * 4;
        float run = fmaxf(acc[0], 0.f);
        int cur = segs[eb];
#pragma unroll
        for (int r = 1; r < 4; r++) {
            int sg = segs[eb + r];
            float v = fmaxf(acc[r], 0.f);
            if (sg != cur) {
                atomicAdd(&hacc[cur][c2], run);
                run = v; cur = sg;
            } else {
                run += v;
            }
        }
        atomicAdd(&hacc[cur][c2], run);
    }
    __syncthreads();
    // One global atomic row per distinct dst in the tile (~1.5 avg).
    for (int i = t; i < 1024; i += 256) {
        int e = i >> 6, c = i & 63;
        if (segs[e] == e) atomicAdd(agg + dsts[e] * 64 + c, hacc[e][c]);
    }
}

// K6: node MLP l1 + BN -> d_out. MFMA, 64 nodes/block.
__global__ __launch_bounds__(256) void k_node_l1(
    const u16* __restrict__ n1l1, const float* __restrict__ agg,
    const u16* __restrict__ Wfn1c, const void* __restrict__ bfn1,
    const void* __restrict__ g1, const void* __restrict__ b1,
    const void* __restrict__ rm1, const void* __restrict__ rv1,
    void* __restrict__ out, const int* __restrict__ mf) {
    int m = mf[0];
    __shared__ __align__(16) u16 fs[64][136];
    int t = threadIdx.x;
    int n0 = blockIdx.x * 64;
    {
        int col = t & 127;
        int rbase = t >> 7;
#pragma unroll
        for (int i = 0; i < 32; i++) {
            int row = rbase + 2 * i;
            int n = n0 + row;
            float v = 0.f;
            if (n < NN) v = (col < 64) ? agg[n * 64 + col] : bfu(n1l1[n * 64 + col - 64]);
            fs[row][col] = f2bf(v);
        }
    }
    __syncthreads();
    int lane = t & 63, w = t >> 6, q = lane >> 4, nidx = lane & 15;
    const u16* ar = &fs[w * 16 + nidx][0];
    short8 a0 = *(const short8*)&ar[q * 8];
    short8 a1 = *(const short8*)&ar[32 + q * 8];
    short8 a2 = *(const short8*)&ar[64 + q * 8];
    short8 a3 = *(const short8*)&ar[96 + q * 8];
#pragma unroll
    for (int jt = 0; jt < 8; jt++) {
        int j = jt * 16 + nidx;
        const u16* wr = Wfn1c + j * 128;
        floatx4 acc = {0.f, 0.f, 0.f, 0.f};
        acc = __builtin_amdgcn_mfma_f32_16x16x32_bf16(a0, *(const short8*)&wr[q * 8], acc, 0, 0, 0);
        acc = __builtin_amdgcn_mfma_f32_16x16x32_bf16(a1, *(const short8*)&wr[32 + q * 8], acc, 0, 0, 0);
        acc = __builtin_amdgcn_mfma_f32_16x16x32_bf16(a2, *(const short8*)&wr[64 + q * 8], acc, 0, 0, 0);
        acc = __builtin_amdgcn_mfma_f32_16x16x32_bf16(a3, *(const short8*)&wr[96 + q * 8], acc, 0, 0, 0);
        float bias = ldf(bfn1, j, m);
        float sc = ldf(g1, j, m) * rsqrtf(ldf(rv1, j, m) + BN_EPS);
        float sh = ldf(b1, j, m) - ldf(rm1, j, m) * sc;
#pragma unroll
        for (int r = 0; r < 4; r++) {
            int row = w * 16 + q * 4 + r;
            int n = n0 + row;
            if (n < NN) {
                float v = fmaxf(acc[r] + bias, 0.f) * sc + sh;
                if (m) ((float*)out)[n * 128 + j] = v;
                else   ((u16*)out)[n * 128 + j] = f2bf(v);
            }
        }
    }
}

extern "C" void kernel_launch(void* const* d_in, const int* in_sizes, int n_in,
                              void* d_out, int out_size, void* d_ws, size_t ws_size,
                              hipStream_t stream) {
    const void* x    = d_in[0];
    const void* ea   = d_in[1];
    const int*  ei   = (const int*)d_in[2];
    const void* Wn0  = d_in[3];
    const void* We0  = d_in[4];
    const void* Wfn0 = d_in[5];
    const void* bfn0 = d_in[6];
    const void* Wfe0 = d_in[7];
    const void* bfe0 = d_in[8];
    const void* g0   = d_in[9];
    const void* b0   = d_in[10];
    const void* rm0  = d_in[11];
    const void* rv0  = d_in[12];
    const void* Wn1  = d_in[13];
    const void* We1  = d_in[14];
    const void* Wfn1 = d_in[15];
    const void* bfn1 = d_in[16];
    // d_in[17]/d_in[18] (l1_Wfe/l1_bfe): dead — layer-1 edge output discarded
    const void* g1   = d_in[19];
    const void* b1   = d_in[20];
    const void* rm1  = d_in[21];
    const void* rv1  = d_in[22];

    float* wsf    = (float*)d_ws;
    float* agg    = wsf;                          // 3,200,000 f32
    u16*   n1l0   = (u16*)(wsf + 3200000);        // 3.2M u16
    u16*   n1l1   = (u16*)(wsf + 4800000);        // 3.2M u16
    float* sp     = wsf + 6400000;                // 50,000
    float* sn     = wsf + 6450000;                // 50,000
    int*   cnt    = (int*)(wsf + 6500000);        // 50,000
    int*   cursor = (int*)(wsf + 6600004);        // 50,000
    int*   bsum   = (int*)(wsf + 6650004);        // 256
    float* PN     = wsf + 6650260;                // 256
    u16*   Wc     = (u16*)(wsf + 6650516);        // 65,536 u16 canonical weights
    int*   mode   = (int*)(wsf + 6683284);        // 1
    int2*  edata  = (int2*)(wsf + 6683288);       // 1,600,000 x 8B (dst-sorted edge records)
    u16* Wfe0c = Wc;
    u16* We1c  = Wc + 16384;
    u16* Wfn0c = Wc + 24576;
    u16* Wn1c  = Wc + 40960;
    u16* Wfn1c = Wc + 49152;

    // Zero sp + sn + cnt (contiguous) and agg (atomic-accumulated).
    hipMemsetAsync(sp, 0, 150000 * sizeof(float), stream);
    hipMemsetAsync(agg, 0, 3200000 * sizeof(float), stream);

    k_detect<<<1, 256, 0, stream>>>((const u16*)x, mode);
    k_cvtw<<<256, 256, 0, stream>>>(Wfe0, We1, Wfn0, Wn1, Wfn1, Wc, mode);
    k_enc0<<<12500, 256, 0, stream>>>(x, Wn0, n1l0, mode);
    k_esum<<<6250, 256, 0, stream>>>(ea, ei, sp, sn, cnt, mode);
    k_scan1<<<NSCAN, 256, 0, stream>>>(cnt, bsum);
    k_scan2<<<1, 256, 0, stream>>>(bsum);
    k_scan3<<<NSCAN, 256, 0, stream>>>(cnt, bsum, cursor);
    k_pn<<<1, 128, 0, stream>>>(We0, Wfe0, PN, mode);
    k_scatter<<<6250, 256, 0, stream>>>(ea, ei, cursor, edata, mode);
    k_node_l0<<<782, 256, 0, stream>>>(n1l0, sp, sn, We0, Wfn0c, bfn0,
                                       g0, b0, rm0, rv0, Wn1c, n1l1, mode);
    k_edge3<<<NE / 16, 256, 0, stream>>>(edata, n1l0, Wfe0c, bfe0, PN, We1c, agg, mode);
    k_node_l1<<<782, 256, 0, stream>>>(n1l1, agg, Wfn1c, bfn1,
                                       g1, b1, rm1, rv1, d_out, mode);
}

// Round 4
// 765.023 us; speedup vs baseline: 1.4758x; 1.1824x over previous
//
#include <hip/hip_runtime.h>

typedef unsigned short u16;
typedef __attribute__((ext_vector_type(8))) short short8;
typedef __attribute__((ext_vector_type(4))) float floatx4;

#define NN 50000
#define NE 1600000
#define BN_EPS 1e-5f
#define NSCAN 196             // ceil(NN/256)
#define TPB 8                 // 16-edge tiles per k_edge4 block

__device__ __forceinline__ float bfu(u16 u) {
    union { unsigned u32; float f; } v; v.u32 = ((unsigned)u) << 16; return v.f;
}
__device__ __forceinline__ u16 f2bf(float f) {
    union { float f; unsigned u; } v; v.f = f;
    unsigned r = v.u + 0x7FFFu + ((v.u >> 16) & 1u);
    return (u16)(r >> 16);
}
// mode m: 1 = buffers hold float32, 0 = buffers hold bf16
__device__ __forceinline__ float ldf(const void* p, int i, int m) {
    return m ? ((const float*)p)[i] : bfu(((const u16*)p)[i]);
}

// K0b: canonicalize all MFMA-consumed weights to bf16 ws copies, with INLINE dtype
// detection (each block recomputes mode from x; block 0 publishes it for later kernels).
// Layout in dst: Wfe0[16384] | We1[8192] | Wfn0[16384] | Wn1[8192] | Wfn1[16384]
__global__ __launch_bounds__(256) void k_cvtw(const u16* __restrict__ x,
                                              const void* __restrict__ W0, const void* __restrict__ W1,
                                              const void* __restrict__ W2, const void* __restrict__ W3,
                                              const void* __restrict__ W4,
                                              u16* __restrict__ dst, int* __restrict__ mode) {
    int t = threadIdx.x;
    __shared__ float sred[4];
    float mx = 0.f;
    for (int i = t; i < 4096; i += 256) mx = fmaxf(mx, fabsf(bfu(x[i])));
#pragma unroll
    for (int o = 32; o > 0; o >>= 1) mx = fmaxf(mx, __shfl_down(mx, o));
    if ((t & 63) == 0) sred[t >> 6] = mx;
    __syncthreads();
    float m2 = fmaxf(fmaxf(sred[0], sred[1]), fmaxf(sred[2], sred[3]));
    int m = (m2 > 1e4f) ? 1 : 0;
    if (blockIdx.x == 0 && t == 0) mode[0] = m;
    int i = blockIdx.x * 256 + t;   // 65536 total
    const void* src; int off;
    if (i < 16384)      { src = W0; off = i; }
    else if (i < 24576) { src = W1; off = i - 16384; }
    else if (i < 40960) { src = W2; off = i - 24576; }
    else if (i < 49152) { src = W3; off = i - 40960; }
    else                { src = W4; off = i - 49152; }
    dst[i] = m ? f2bf(((const float*)src)[off]) : ((const u16*)src)[off];
}

// K1h: fused {node encoder l0 (16 nodes/block)} + {dst-degree histogram} via block-range split.
__global__ __launch_bounds__(256) void k_enc0h(const void* __restrict__ x, const void* __restrict__ Wn,
                                               u16* __restrict__ n1, const int* __restrict__ ei,
                                               int* __restrict__ cnt, const int* __restrict__ mf) {
    int b = blockIdx.x;
    int t = threadIdx.x;
    if (b >= 3125) {   // histogram part: 6250 blocks
        int e = (b - 3125) * 256 + t;
        atomicAdd(cnt + ei[NE + e], 1);
        return;
    }
    int m = mf[0];
    __shared__ float Wns[64 * 17];
    __shared__ float xsh[16][17];
    int n0 = b * 16;
    for (int i = t; i < 1024; i += 256) Wns[(i >> 4) * 17 + (i & 15)] = ldf(Wn, i, m);
    xsh[t >> 4][t & 15] = ldf(x, n0 * 16 + t, m);
    __syncthreads();
    int c = t & 63, ng = t >> 6;   // ng: node group 0..3, nodes ng*4..ng*4+3
    float a0 = 0.f, a1 = 0.f, a2 = 0.f, a3 = 0.f;
#pragma unroll
    for (int k = 0; k < 16; k++) {
        float wv = Wns[c * 17 + k];
        a0 += xsh[ng * 4 + 0][k] * wv;
        a1 += xsh[ng * 4 + 1][k] * wv;
        a2 += xsh[ng * 4 + 2][k] * wv;
        a3 += xsh[ng * 4 + 3][k] * wv;
    }
    n1[(n0 + ng * 4 + 0) * 64 + c] = f2bf(fmaxf(a0, 0.f));
    n1[(n0 + ng * 4 + 1) * 64 + c] = f2bf(fmaxf(a1, 0.f));
    n1[(n0 + ng * 4 + 2) * 64 + c] = f2bf(fmaxf(a2, 0.f));
    n1[(n0 + ng * 4 + 3) * 64 + c] = f2bf(fmaxf(a3, 0.f));
}

// Scan phase 1: per-256-block sums of cnt
__global__ __launch_bounds__(256) void k_scan1(const int* __restrict__ cnt, int* __restrict__ bsum) {
    int t = threadIdx.x;
    int idx = blockIdx.x * 256 + t;
    int v = (idx < NN) ? cnt[idx] : 0;
#pragma unroll
    for (int o = 32; o > 0; o >>= 1) v += __shfl_down(v, o);
    __shared__ int s[4];
    if ((t & 63) == 0) s[t >> 6] = v;
    __syncthreads();
    if (t == 0) bsum[blockIdx.x] = s[0] + s[1] + s[2] + s[3];
}

// Scan phase 2 + K_PN fold (both tiny single-block jobs).
__global__ __launch_bounds__(256) void k_scan2pn(int* __restrict__ bsum,
                                                 const void* __restrict__ We0, const void* __restrict__ Wfe0,
                                                 float* __restrict__ PN, const int* __restrict__ mf) {
    __shared__ int sh[256];
    int t = threadIdx.x;
    int v = (t < NSCAN) ? bsum[t] : 0;
    sh[t] = v;
    __syncthreads();
    for (int o = 1; o < 256; o <<= 1) {
        int u = (t >= o) ? sh[t - o] : 0;
        __syncthreads();
        sh[t] += u;
        __syncthreads();
    }
    if (t < NSCAN) bsum[t] = sh[t] - v;   // exclusive
    if (t < 128) {
        int m = mf[0];
        float p = 0.f, n = 0.f;
        for (int k = 0; k < 64; k++) {
            float w = ldf(We0, k, m);
            float wf = ldf(Wfe0, t * 128 + 64 + k, m);
            p += fmaxf(w, 0.f) * wf;
            n += fminf(w, 0.f) * wf;
        }
        PN[t] = p; PN[128 + t] = n;
    }
}

// Scan phase 3: per-block exclusive scan + offset -> cursor[] (scatter cursors)
__global__ __launch_bounds__(256) void k_scan3(const int* __restrict__ cnt, const int* __restrict__ bsum,
                                               int* __restrict__ cursor) {
    __shared__ int sh[256];
    int t = threadIdx.x;
    int idx = blockIdx.x * 256 + t;
    int v = (idx < NN) ? cnt[idx] : 0;
    sh[t] = v;
    __syncthreads();
    for (int o = 1; o < 256; o <<= 1) {
        int u = (t >= o) ? sh[t - o] : 0;
        __syncthreads();
        sh[t] += u;
        __syncthreads();
    }
    int excl = sh[t] - v + bsum[blockIdx.x];
    if (idx < NN) cursor[idx] = excl;
}

// Scatter: one packed 8B record per edge into its dst-sorted slot; also the
// per-node positive/negative edge_attr sums (moved here from the old k_esum).
__global__ __launch_bounds__(256) void k_scatter(const void* __restrict__ ea, const int* __restrict__ ei,
                                                 int* __restrict__ cursor, int2* __restrict__ edata,
                                                 float* __restrict__ sp, float* __restrict__ sn,
                                                 const int* __restrict__ mf) {
    int m = mf[0];
    int e = blockIdx.x * 256 + threadIdx.x;
    int d = ei[NE + e];
    int s = ei[e];
    float a = ldf(ea, e, m);
    int p = atomicAdd(cursor + d, 1);
    int2 v;
    v.x = (int)((unsigned)s | ((unsigned)d << 16));
    v.y = __float_as_int(a);
    edata[p] = v;
    if (a > 0.f) atomicAdd(sp + d, a);
    else if (a < 0.f) atomicAdd(sn + d, a);
}

// K34: fused node MLP l0 + BN + node encoder l1 -> n1_l1 [50000 x 64] bf16. MFMA, 64 nodes/block.
__global__ __launch_bounds__(256) void k_node_l0(
    const u16* __restrict__ n1l0, const float* __restrict__ sp, const float* __restrict__ sn,
    const void* __restrict__ We0, const u16* __restrict__ Wfn0c, const void* __restrict__ bfn0,
    const void* __restrict__ g0, const void* __restrict__ b0,
    const void* __restrict__ rm0, const void* __restrict__ rv0,
    const u16* __restrict__ Wn1c, u16* __restrict__ n1l1, const int* __restrict__ mf) {
    int m = mf[0];
    __shared__ __align__(16) u16 fs[64][136];
    __shared__ __align__(16) u16 xs[64][136];
    int t = threadIdx.x;
    int n0 = blockIdx.x * 64;
    {   // fs[row][col] = concat(analytic agg_l0, n1_l0), bf16
        int col = t & 127;
        int rbase = t >> 7;              // 0 or 1
        float wp = 0.f, wn = 0.f;
        if (col < 64) { float w0 = ldf(We0, col, m); wp = fmaxf(w0, 0.f); wn = fminf(w0, 0.f); }
#pragma unroll
        for (int i = 0; i < 32; i++) {
            int row = rbase + 2 * i;
            int n = n0 + row;
            float v = 0.f;
            if (n < NN) v = (col < 64) ? (wp * sp[n] + wn * sn[n]) : bfu(n1l0[n * 64 + col - 64]);
            fs[row][col] = f2bf(v);
        }
    }
    __syncthreads();
    int lane = t & 63, w = t >> 6, q = lane >> 4, nidx = lane & 15;
    {
        const u16* ar = &fs[w * 16 + nidx][0];
        short8 a0 = *(const short8*)&ar[q * 8];
        short8 a1 = *(const short8*)&ar[32 + q * 8];
        short8 a2 = *(const short8*)&ar[64 + q * 8];
        short8 a3 = *(const short8*)&ar[96 + q * 8];
#pragma unroll
        for (int jt = 0; jt < 8; jt++) {
            int j = jt * 16 + nidx;
            const u16* wr = Wfn0c + j * 128;
            floatx4 acc = {0.f, 0.f, 0.f, 0.f};
            acc = __builtin_amdgcn_mfma_f32_16x16x32_bf16(a0, *(const short8*)&wr[q * 8], acc, 0, 0, 0);
            acc = __builtin_amdgcn_mfma_f32_16x16x32_bf16(a1, *(const short8*)&wr[32 + q * 8], acc, 0, 0, 0);
            acc = __builtin_amdgcn_mfma_f32_16x16x32_bf16(a2, *(const short8*)&wr[64 + q * 8], acc, 0, 0, 0);
            acc = __builtin_amdgcn_mfma_f32_16x16x32_bf16(a3, *(const short8*)&wr[96 + q * 8], acc, 0, 0, 0);
            float bias = ldf(bfn0, j, m);
            float sc = ldf(g0, j, m) * rsqrtf(ldf(rv0, j, m) + BN_EPS);
            float sh = ldf(b0, j, m) - ldf(rm0, j, m) * sc;
#pragma unroll
            for (int r = 0; r < 4; r++) {
                int row = w * 16 + q * 4 + r;
                xs[row][j] = f2bf(fmaxf(acc[r] + bias, 0.f) * sc + sh);
            }
        }
    }
    __syncthreads();
    {
        const u16* ar = &xs[w * 16 + nidx][0];
        short8 a0 = *(const short8*)&ar[q * 8];
        short8 a1 = *(const short8*)&ar[32 + q * 8];
        short8 a2 = *(const short8*)&ar[64 + q * 8];
        short8 a3 = *(const short8*)&ar[96 + q * 8];
#pragma unroll
        for (int jt = 0; jt < 4; jt++) {
            int j = jt * 16 + nidx;
            const u16* wr = Wn1c + j * 128;
            floatx4 acc = {0.f, 0.f, 0.f, 0.f};
            acc = __builtin_amdgcn_mfma_f32_16x16x32_bf16(a0, *(const short8*)&wr[q * 8], acc, 0, 0, 0);
            acc = __builtin_amdgcn_mfma_f32_16x16x32_bf16(a1, *(const short8*)&wr[32 + q * 8], acc, 0, 0, 0);
            acc = __builtin_amdgcn_mfma_f32_16x16x32_bf16(a2, *(const short8*)&wr[64 + q * 8], acc, 0, 0, 0);
            acc = __builtin_amdgcn_mfma_f32_16x16x32_bf16(a3, *(const short8*)&wr[96 + q * 8], acc, 0, 0, 0);
#pragma unroll
            for (int r = 0; r < 4; r++) {
                int row = w * 16 + q * 4 + r;
                int n = n0 + row;
                if (n < NN) n1l1[n * 64 + j] = f2bf(fmaxf(acc[r], 0.f));
            }
        }
    }
}

// K5v4: lean fused edge pipeline on dst-sorted edges. TPB 16-edge tiles per block.
// Weights/bias/PN hoisted to registers ONCE per block. GEMM1 uses the distributive
// split h0@W^T = n1[src]@W^T + n1[dst]@W^T with operand-swapped MFMA (D: row=channel,
// col=edge) so A-fragments load straight from global (no gather/LDS/convert phase).
// GEMM2 as r2; per-lane run-merge over the lane's 4 sorted edges -> direct global atomics.
__global__ __launch_bounds__(256) void k_edge4(
    const int2* __restrict__ edata, const u16* __restrict__ n1l0,
    const u16* __restrict__ Wfe0c, const void* __restrict__ bfe0,
    const float* __restrict__ PN, const u16* __restrict__ We1c,
    float* __restrict__ agg, const int* __restrict__ mf) {
    int m = mf[0];
    __shared__ __align__(16) u16 h1s[2][16][136];
    int t = threadIdx.x;
    int lane = t & 63, w = t >> 6, q = lane >> 4, nidx = lane & 15;
    // ---- per-block register hoists ----
    short8 wA[2][2];           // GEMM1 A-frags (swapped): W row = jt*16+nidx
    float bias[2][4], Pv[2][4], Nv[2][4];
#pragma unroll
    for (int jj = 0; jj < 2; jj++) {
        int jt = 2 * w + jj;
        const u16* wr = Wfe0c + (jt * 16 + nidx) * 128;
        wA[jj][0] = *(const short8*)&wr[q * 8];
        wA[jj][1] = *(const short8*)&wr[32 + q * 8];
#pragma unroll
        for (int r = 0; r < 4; r++) {
            int ch = jt * 16 + q * 4 + r;
            bias[jj][r] = ldf(bfe0, ch, m);
            Pv[jj][r] = PN[ch];
            Nv[jj][r] = PN[128 + ch];
        }
    }
    int c2 = w * 16 + nidx;
    const u16* wr2 = We1c + c2 * 128;
    short8 wB0 = *(const short8*)&wr2[q * 8];
    short8 wB1 = *(const short8*)&wr2[32 + q * 8];
    short8 wB2 = *(const short8*)&wr2[64 + q * 8];
    short8 wB3 = *(const short8*)&wr2[96 + q * 8];

    int e0 = blockIdx.x * (16 * TPB);
    // ---- software-pipelined prologue: tile 0 loads ----
    int2 ed = edata[e0 + nidx];
    const u16* srow = n1l0 + ((size_t)(((unsigned)ed.x) & 0xFFFFu)) * 64;
    const u16* drow = n1l0 + ((size_t)(((unsigned)ed.x) >> 16)) * 64;
    short8 as0 = *(const short8*)&srow[q * 8];
    short8 as1 = *(const short8*)&srow[32 + q * 8];
    short8 ad0 = *(const short8*)&drow[q * 8];
    short8 ad1 = *(const short8*)&drow[32 + q * 8];

    for (int tile = 0; tile < TPB; tile++) {
        int2 edc = ed;
        short8 cs0 = as0, cs1 = as1, cd0 = ad0, cd1 = ad1;
        if (tile + 1 < TPB) {   // issue next tile's loads early (hidden under GEMMs)
            ed = edata[e0 + (tile + 1) * 16 + nidx];
            srow = n1l0 + ((size_t)(((unsigned)ed.x) & 0xFFFFu)) * 64;
            drow = n1l0 + ((size_t)(((unsigned)ed.x) >> 16)) * 64;
            as0 = *(const short8*)&srow[q * 8];
            as1 = *(const short8*)&srow[32 + q * 8];
            ad0 = *(const short8*)&drow[q * 8];
            ad1 = *(const short8*)&drow[32 + q * 8];
        }
        float aev = __int_as_float(edc.y);
        u16* hp = &h1s[tile & 1][0][0];
        // GEMM1 (swapped): channels jt*16+q*4+r for edge nidx
#pragma unroll
        for (int jj = 0; jj < 2; jj++) {
            floatx4 acc = {0.f, 0.f, 0.f, 0.f};
            acc = __builtin_amdgcn_mfma_f32_16x16x32_bf16(wA[jj][0], cs0, acc, 0, 0, 0);
            acc = __builtin_amdgcn_mfma_f32_16x16x32_bf16(wA[jj][1], cs1, acc, 0, 0, 0);
            acc = __builtin_amdgcn_mfma_f32_16x16x32_bf16(wA[jj][0], cd0, acc, 0, 0, 0);
            acc = __builtin_amdgcn_mfma_f32_16x16x32_bf16(wA[jj][1], cd1, acc, 0, 0, 0);
            float v0 = fmaxf(acc[0] + bias[jj][0] + aev * (aev > 0.f ? Pv[jj][0] : Nv[jj][0]), 0.f);
            float v1 = fmaxf(acc[1] + bias[jj][1] + aev * (aev > 0.f ? Pv[jj][1] : Nv[jj][1]), 0.f);
            float v2 = fmaxf(acc[2] + bias[jj][2] + aev * (aev > 0.f ? Pv[jj][2] : Nv[jj][2]), 0.f);
            float v3 = fmaxf(acc[3] + bias[jj][3] + aev * (aev > 0.f ? Pv[jj][3] : Nv[jj][3]), 0.f);
            unsigned lo = (unsigned)f2bf(v0) | ((unsigned)f2bf(v1) << 16);
            unsigned hi = (unsigned)f2bf(v2) | ((unsigned)f2bf(v3) << 16);
            uint2 pk; pk.x = lo; pk.y = hi;
            *(uint2*)&hp[nidx * 136 + w * 32 + jj * 16 + q * 4] = pk;
        }
        __syncthreads();
        // GEMM2: e1' = relu(h1 @ We1^T); D row=q*4+r=edge, col=nidx -> channel c2
        const u16* arow = &h1s[tile & 1][nidx][0];
        floatx4 acc2 = {0.f, 0.f, 0.f, 0.f};
        acc2 = __builtin_amdgcn_mfma_f32_16x16x32_bf16(*(const short8*)&arow[q * 8], wB0, acc2, 0, 0, 0);
        acc2 = __builtin_amdgcn_mfma_f32_16x16x32_bf16(*(const short8*)&arow[32 + q * 8], wB1, acc2, 0, 0, 0);
        acc2 = __builtin_amdgcn_mfma_f32_16x16x32_bf16(*(const short8*)&arow[64 + q * 8], wB2, acc2, 0, 0, 0);
        acc2 = __builtin_amdgcn_mfma_f32_16x16x32_bf16(*(const short8*)&arow[96 + q * 8], wB3, acc2, 0, 0, 0);
        // dsts of my 4 edges (q*4+r) via shfl of the tile's edge records
        unsigned x0 = (unsigned)__shfl(edc.x, q * 4 + 0);
        unsigned x1 = (unsigned)__shfl(edc.x, q * 4 + 1);
        unsigned x2 = (unsigned)__shfl(edc.x, q * 4 + 2);
        unsigned x3 = (unsigned)__shfl(edc.x, q * 4 + 3);
        unsigned d0 = x0 >> 16, d1 = x1 >> 16, d2 = x2 >> 16, d3 = x3 >> 16;
        float v0 = fmaxf(acc2[0], 0.f);
        float v1 = fmaxf(acc2[1], 0.f);
        float v2 = fmaxf(acc2[2], 0.f);
        float v3 = fmaxf(acc2[3], 0.f);
        float run = v0; unsigned cur = d0;
        if (d1 != cur) { atomicAdd(agg + cur * 64 + c2, run); run = v1; cur = d1; } else run += v1;
        if (d2 != cur) { atomicAdd(agg + cur * 64 + c2, run); run = v2; cur = d2; } else run += v2;
        if (d3 != cur) { atomicAdd(agg + cur * 64 + c2, run); run = v3; cur = d3; } else run += v3;
        atomicAdd(agg + cur * 64 + c2, run);
        // one barrier per tile: double-buffered h1s makes write(t+2) vs read(t) safe
    }
}

// K6: node MLP l1 + BN -> d_out. MFMA, 64 nodes/block.
__global__ __launch_bounds__(256) void k_node_l1(
    const u16* __restrict__ n1l1, const float* __restrict__ agg,
    const u16* __restrict__ Wfn1c, const void* __restrict__ bfn1,
    const void* __restrict__ g1, const void* __restrict__ b1,
    const void* __restrict__ rm1, const void* __restrict__ rv1,
    void* __restrict__ out, const int* __restrict__ mf) {
    int m = mf[0];
    __shared__ __align__(16) u16 fs[64][136];
    int t = threadIdx.x;
    int n0 = blockIdx.x * 64;
    {
        int col = t & 127;
        int rbase = t >> 7;
#pragma unroll
        for (int i = 0; i < 32; i++) {
            int row = rbase + 2 * i;
            int n = n0 + row;
            float v = 0.f;
            if (n < NN) v = (col < 64) ? agg[n * 64 + col] : bfu(n1l1[n * 64 + col - 64]);
            fs[row][col] = f2bf(v);
        }
    }
    __syncthreads();
    int lane = t & 63, w = t >> 6, q = lane >> 4, nidx = lane & 15;
    const u16* ar = &fs[w * 16 + nidx][0];
    short8 a0 = *(const short8*)&ar[q * 8];
    short8 a1 = *(const short8*)&ar[32 + q * 8];
    short8 a2 = *(const short8*)&ar[64 + q * 8];
    short8 a3 = *(const short8*)&ar[96 + q * 8];
#pragma unroll
    for (int jt = 0; jt < 8; jt++) {
        int j = jt * 16 + nidx;
        const u16* wr = Wfn1c + j * 128;
        floatx4 acc = {0.f, 0.f, 0.f, 0.f};
        acc = __builtin_amdgcn_mfma_f32_16x16x32_bf16(a0, *(const short8*)&wr[q * 8], acc, 0, 0, 0);
        acc = __builtin_amdgcn_mfma_f32_16x16x32_bf16(a1, *(const short8*)&wr[32 + q * 8], acc, 0, 0, 0);
        acc = __builtin_amdgcn_mfma_f32_16x16x32_bf16(a2, *(const short8*)&wr[64 + q * 8], acc, 0, 0, 0);
        acc = __builtin_amdgcn_mfma_f32_16x16x32_bf16(a3, *(const short8*)&wr[96 + q * 8], acc, 0, 0, 0);
        float bias = ldf(bfn1, j, m);
        float sc = ldf(g1, j, m) * rsqrtf(ldf(rv1, j, m) + BN_EPS);
        float sh = ldf(b1, j, m) - ldf(rm1, j, m) * sc;
#pragma unroll
        for (int r = 0; r < 4; r++) {
            int row = w * 16 + q * 4 + r;
            int n = n0 + row;
            if (n < NN) {
                float v = fmaxf(acc[r] + bias, 0.f) * sc + sh;
                if (m) ((float*)out)[n * 128 + j] = v;
                else   ((u16*)out)[n * 128 + j] = f2bf(v);
            }
        }
    }
}

extern "C" void kernel_launch(void* const* d_in, const int* in_sizes, int n_in,
                              void* d_out, int out_size, void* d_ws, size_t ws_size,
                              hipStream_t stream) {
    const void* x    = d_in[0];
    const void* ea   = d_in[1];
    const int*  ei   = (const int*)d_in[2];
    const void* Wn0  = d_in[3];
    const void* We0  = d_in[4];
    const void* Wfn0 = d_in[5];
    const void* bfn0 = d_in[6];
    const void* Wfe0 = d_in[7];
    const void* bfe0 = d_in[8];
    const void* g0   = d_in[9];
    const void* b0   = d_in[10];
    const void* rm0  = d_in[11];
    const void* rv0  = d_in[12];
    const void* Wn1  = d_in[13];
    const void* We1  = d_in[14];
    const void* Wfn1 = d_in[15];
    const void* bfn1 = d_in[16];
    // d_in[17]/d_in[18] (l1_Wfe/l1_bfe): dead — layer-1 edge output discarded
    const void* g1   = d_in[19];
    const void* b1   = d_in[20];
    const void* rm1  = d_in[21];
    const void* rv1  = d_in[22];

    float* wsf    = (float*)d_ws;
    float* agg    = wsf;                          // 3,200,000 f32
    u16*   n1l0   = (u16*)(wsf + 3200000);        // 3.2M u16
    u16*   n1l1   = (u16*)(wsf + 4800000);        // 3.2M u16
    float* sp     = wsf + 6400000;                // 50,000
    float* sn     = wsf + 6450000;                // 50,000
    int*   cnt    = (int*)(wsf + 6500000);        // 50,000
    int*   cursor = (int*)(wsf + 6550000);        // 50,000
    int*   bsum   = (int*)(wsf + 6600000);        // 256
    float* PN     = wsf + 6600256;                // 256
    u16*   Wc     = (u16*)(wsf + 6600512);        // 65,536 u16 canonical weights
    int*   mode   = (int*)(wsf + 6633280);        // 1
    int2*  edata  = (int2*)(wsf + 6633284);       // 1,600,000 x 8B (dst-sorted edge records)
    u16* Wfe0c = Wc;
    u16* We1c  = Wc + 16384;
    u16* Wfn0c = Wc + 24576;
    u16* Wn1c  = Wc + 40960;
    u16* Wfn1c = Wc + 49152;

    // Zero sp + sn + cnt (contiguous) and agg (atomic-accumulated).
    hipMemsetAsync(sp, 0, 150000 * sizeof(float), stream);
    hipMemsetAsync(agg, 0, 3200000 * sizeof(float), stream);

    k_cvtw<<<256, 256, 0, stream>>>((const u16*)x, Wfe0, We1, Wfn0, Wn1, Wfn1, Wc, mode);
    k_enc0h<<<9375, 256, 0, stream>>>(x, Wn0, n1l0, ei, cnt, mode);
    k_scan1<<<NSCAN, 256, 0, stream>>>(cnt, bsum);
    k_scan2pn<<<1, 256, 0, stream>>>(bsum, We0, Wfe0, PN, mode);
    k_scan3<<<NSCAN, 256, 0, stream>>>(cnt, bsum, cursor);
    k_scatter<<<6250, 256, 0, stream>>>(ea, ei, cursor, edata, sp, sn, mode);
    k_node_l0<<<782, 256, 0, stream>>>(n1l0, sp, sn, We0, Wfn0c, bfn0,
                                       g0, b0, rm0, rv0, Wn1c, n1l1, mode);
    k_edge4<<<NE / (16 * TPB), 256, 0, stream>>>(edata, n1l0, Wfe0c, bfe0, PN, We1c, agg, mode);
    k_node_l1<<<782, 256, 0, stream>>>(n1l1, agg, Wfn1c, bfn1,
                                       g1, b1, rm1, rv1, d_out, mode);
}